// Round 4
// baseline (4309.710 us; speedup 1.0000x reference)
//
#include <hip/hip_runtime.h>
#include <math.h>

#define B_ 16
#define N_ 2048
#define KNN 20
#define BN_EPS 1e-5f
#define SLOPE 0.01f

// ============================================================ xx = sum_d x^2
__global__ __launch_bounds__(256) void xx_kernel(const float* __restrict__ xin, long bstr, int D,
                                                 float* __restrict__ xx) {
  int i = blockIdx.x * 256 + threadIdx.x;
  if (i >= B_ * N_) return;
  int b = i >> 11, n = i & (N_ - 1);
  const float* p = xin + (long)b * bstr + n;
  float s = 0.f;
#pragma unroll 1
  for (int d = 0; d < D; ++d) { float v = p[(long)d * N_]; s = fmaf(v, v, s); }
  xx[i] = s;
}

// ============================================================ (B,D,N) -> per-batch (N,D)
__global__ __launch_bounds__(256) void transpose_kernel(const float* __restrict__ xin, long bstr,
                                                        float* __restrict__ xT, long xTbstr, int D) {
  __shared__ float s[32][65];
  int b = blockIdx.y;
  int n0 = blockIdx.x * 64;
  int tid = threadIdx.x;
  const float* xb = xin + (long)b * bstr;
  float* tb = xT + (long)b * xTbstr;
  for (int dc = 0; dc < D; dc += 32) {
    for (int i = tid; i < 32 * 64; i += 256) {
      int d = i >> 6, n = i & 63;
      s[d][n] = (dc + d < D) ? xb[(long)(dc + d) * N_ + n0 + n] : 0.f;
    }
    __syncthreads();
    for (int i = tid; i < 64 * 32; i += 256) {
      int n = i >> 5, d = i & 31;
      if (dc + d < D) tb[(long)(n0 + n) * D + dc + d] = s[d][n];
    }
    __syncthreads();
  }
}

// ============================================================ blocked gsa:
//  block = 4 waves x 4 rows = 16 rows; x staged in LDS d-chunks (shared by all 16 rows)
//  chunk-max top-20 with wave-uniform winner update; agg fused online into top-k loop
template <int D>
__global__ __launch_bounds__(256) void gsa_blk_kernel(const float* __restrict__ xin, long bstr,
                                                      const float* __restrict__ xT, long xTbstr,
                                                      const float* __restrict__ xx,
                                                      float* __restrict__ agg, long aggbstr) {
  constexpr int TCH = (D < 8) ? D : 8;          // staged d-rows per chunk
  constexpr int NV = (D + 63) / 64;             // agg accumulators per lane
  __shared__ float xs[TCH][2048];
  __shared__ float xn_s[16][(D + 3) & ~3];
  int tid = threadIdx.x, w = tid >> 6, lane = tid & 63;
  int r0 = blockIdx.x * 16;
  int b = r0 >> 11;
  int n0 = r0 & (N_ - 1);
  const float* xb = xin + (long)b * bstr;
  const float* tb = xT + (long)b * xTbstr;
  // center features for the block's 16 rows
  for (int i = tid; i < 16 * D; i += 256) {
    int rr = i / D, d = i - rr * D;
    xn_s[rr][d] = tb[(long)(n0 + rr) * D + d];
  }
  float acc[4][8][4] = {};   // [row r][chunk c][j] ; col = c*256 + lane*4 + j
#pragma unroll 1
  for (int d0 = 0; d0 < D; d0 += TCH) {
    __syncthreads();
    for (int i = tid; i < TCH * 512; i += 256) {
      int dr = i >> 9, c4 = i & 511;
      *(float4*)&xs[dr][c4 << 2] = *(const float4*)(xb + (long)(d0 + dr) * N_ + (c4 << 2));
    }
    __syncthreads();
#pragma unroll
    for (int dr = 0; dr < TCH; ++dr) {
      float4 v[8];
      const float4* xs4 = (const float4*)xs[dr];
#pragma unroll
      for (int c = 0; c < 8; ++c) v[c] = xs4[c * 64 + lane];
#pragma unroll
      for (int r = 0; r < 4; ++r) {
        float xnd = xn_s[(w << 2) + r][d0 + dr];
#pragma unroll
        for (int c = 0; c < 8; ++c) {
          acc[r][c][0] = fmaf(xnd, v[c].x, acc[r][c][0]);
          acc[r][c][1] = fmaf(xnd, v[c].y, acc[r][c][1]);
          acc[r][c][2] = fmaf(xnd, v[c].z, acc[r][c][2]);
          acc[r][c][3] = fmaf(xnd, v[c].w, acc[r][c][3]);
        }
      }
    }
  }
  // acc -> dist in place: dv = 2*acc - xx[n] - xx[m]
  {
    const float4* xx4 = (const float4*)(xx + (long)b * N_);
    float4 xm[8];
#pragma unroll
    for (int c = 0; c < 8; ++c) xm[c] = xx4[c * 64 + lane];
#pragma unroll
    for (int r = 0; r < 4; ++r) {
      float xxn = xx[(long)b * N_ + n0 + (w << 2) + r];
#pragma unroll
      for (int c = 0; c < 8; ++c) {
        acc[r][c][0] = 2.f * acc[r][c][0] - xxn - xm[c].x;
        acc[r][c][1] = 2.f * acc[r][c][1] - xxn - xm[c].y;
        acc[r][c][2] = 2.f * acc[r][c][2] - xxn - xm[c].z;
        acc[r][c][3] = 2.f * acc[r][c][3] - xxn - xm[c].w;
      }
    }
  }
  // per-row: top-20 + fused softmax/agg
#pragma unroll
  for (int r = 0; r < 4; ++r) {
    int n = n0 + (w << 2) + r;
    float (*a)[4] = acc[r];
    float m8[8];
    int meta8[8];
#pragma unroll
    for (int c = 0; c < 8; ++c) {
      float mm = a[c][0]; int ss = 0;
      if (a[c][1] > mm) { mm = a[c][1]; ss = 1; }
      if (a[c][2] > mm) { mm = a[c][2]; ss = 2; }
      if (a[c][3] > mm) { mm = a[c][3]; ss = 3; }
      m8[c] = mm; meta8[c] = (c << 8) + (lane << 2) + ss;
    }
    float m0 = 0.f, Z = 0.f;
    float ve[NV];
#pragma unroll
    for (int vi = 0; vi < NV; ++vi) ve[vi] = 0.f;
#pragma unroll 1
    for (int it = 0; it < KNN; ++it) {
      float best = m8[0]; int bidx = meta8[0];
#pragma unroll
      for (int c = 1; c < 8; ++c)
        if (m8[c] > best) { best = m8[c]; bidx = meta8[c]; }
#pragma unroll
      for (int off = 1; off < 64; off <<= 1) {
        float ov = __shfl_xor(best, off);
        int oi = __shfl_xor(bidx, off);
        if (ov > best || (ov == best && oi < bidx)) { best = ov; bidx = oi; }
      }
      int ubidx = __builtin_amdgcn_readfirstlane(bidx);
      if (it == 0) m0 = best;
      float e = __expf(best - m0);
      Z += e;
      // online aggregate: ve += e * x[neighbor]
#pragma unroll
      for (int vi = 0; vi < NV; ++vi) {
        int dd = lane + vi * 64;
        if (D >= 64 || dd < D) ve[vi] = fmaf(e, tb[(long)ubidx * D + dd], ve[vi]);
      }
      // remove winner entry + recompute its chunk max (uniform branches)
      int cw = ubidx >> 8, wl = (ubidx >> 2) & 63, jw = ubidx & 3;
      bool isw = (lane == wl);
#pragma unroll
      for (int c = 0; c < 8; ++c)
        if (c == cw) {
#pragma unroll
          for (int j = 0; j < 4; ++j)
            if (j == jw) a[c][j] = isw ? -3.4e38f : a[c][j];
          float mm = a[c][0]; int ss = 0;
          if (a[c][1] > mm) { mm = a[c][1]; ss = 1; }
          if (a[c][2] > mm) { mm = a[c][2]; ss = 2; }
          if (a[c][3] > mm) { mm = a[c][3]; ss = 3; }
          m8[c] = mm; meta8[c] = (c << 8) + (lane << 2) + ss;
        }
    }
    float rZ = 1.f / Z;
#pragma unroll
    for (int vi = 0; vi < NV; ++vi) {
      int dd = lane + vi * 64;
      if (D >= 64 || dd < D)
        agg[(long)b * aggbstr + (long)dd * N_ + n] = ve[vi] * rZ - xn_s[(w << 2) + r][dd];
    }
  }
}

// ============================================================ small GEMM (64x64 tile) + BN stats
__global__ __launch_bounds__(256) void gemm_bn_kernel(const float* __restrict__ Wm, int O, int K,
                                                      const float* __restrict__ xin, long bstr, int Dx,
                                                      const float* __restrict__ agg, long aggbstr,
                                                      float* __restrict__ y, float* __restrict__ stats) {
  __shared__ __align__(16) float As[16][68];
  __shared__ __align__(16) float Bs[16][68];
  int tid = threadIdx.x;
  int o0 = blockIdx.x * 64;
  int j0 = blockIdx.y * 64;
  int b = j0 >> 11, n0 = j0 & (N_ - 1);
  int ty = tid >> 4, tx = tid & 15;
  float accr[4][4] = {};
  int aK = tid & 15, aO = tid >> 4;
  int bK = tid >> 4, bn4 = (tid & 15) << 2;
  for (int k0 = 0; k0 < K; k0 += 16) {
#pragma unroll
    for (int q = 0; q < 4; ++q) {
      int o = aO + (q << 4);
      As[aK][o] = (k0 + aK < K) ? Wm[(long)(o0 + o) * K + k0 + aK] : 0.f;
    }
    {
      int c = k0 + bK;
      float4 v = {0.f, 0.f, 0.f, 0.f};
      if (c < K) {
        const float* src = (c < Dx) ? xin + (long)b * bstr + (long)c * N_
                                    : agg + (long)b * aggbstr + (long)(c - Dx) * N_;
        v = *(const float4*)(src + n0 + bn4);
      }
      *(float4*)&Bs[bK][bn4] = v;
    }
    __syncthreads();
#pragma unroll
    for (int kk = 0; kk < 16; ++kk) {
      float4 a4 = *(const float4*)&As[kk][ty << 2];
      float4 b4 = *(const float4*)&Bs[kk][tx << 2];
      accr[0][0] = fmaf(a4.x, b4.x, accr[0][0]);
      accr[0][1] = fmaf(a4.x, b4.y, accr[0][1]);
      accr[0][2] = fmaf(a4.x, b4.z, accr[0][2]);
      accr[0][3] = fmaf(a4.x, b4.w, accr[0][3]);
      accr[1][0] = fmaf(a4.y, b4.x, accr[1][0]);
      accr[1][1] = fmaf(a4.y, b4.y, accr[1][1]);
      accr[1][2] = fmaf(a4.y, b4.z, accr[1][2]);
      accr[1][3] = fmaf(a4.y, b4.w, accr[1][3]);
      accr[2][0] = fmaf(a4.z, b4.x, accr[2][0]);
      accr[2][1] = fmaf(a4.z, b4.y, accr[2][1]);
      accr[2][2] = fmaf(a4.z, b4.z, accr[2][2]);
      accr[2][3] = fmaf(a4.z, b4.w, accr[2][3]);
      accr[3][0] = fmaf(a4.w, b4.x, accr[3][0]);
      accr[3][1] = fmaf(a4.w, b4.y, accr[3][1]);
      accr[3][2] = fmaf(a4.w, b4.z, accr[3][2]);
      accr[3][3] = fmaf(a4.w, b4.w, accr[3][3]);
    }
    __syncthreads();
  }
#pragma unroll
  for (int r = 0; r < 4; ++r) {
    int o = o0 + (ty << 2) + r;
    float4 v;
    v.x = accr[r][0]; v.y = accr[r][1]; v.z = accr[r][2]; v.w = accr[r][3];
    *(float4*)(y + ((long)b * O + o) * N_ + n0 + bn4) = v;
    float s1 = v.x + v.y + v.z + v.w;
    float s2 = v.x * v.x + v.y * v.y + v.z * v.z + v.w * v.w;
#pragma unroll
    for (int off = 1; off < 16; off <<= 1) { s1 += __shfl_xor(s1, off); s2 += __shfl_xor(s2, off); }
    if (tx == 0) { atomicAdd(&stats[o], s1); atomicAdd(&stats[O + o], s2); }
  }
}

// ============================================================ big GEMM (128x128x8 tile) + BN stats
//  requires O % 128 == 0, K % 8 == 0. Each thread: 8x8 acc split 4+4 rows/cols 64 apart.
__global__ __launch_bounds__(256) void gemm_bn128_kernel(const float* __restrict__ Wm, int O, int K,
                                                         const float* __restrict__ xin, long bstr, int Dx,
                                                         const float* __restrict__ agg, long aggbstr,
                                                         float* __restrict__ y, float* __restrict__ stats) {
  __shared__ __align__(16) float As[8][132];
  __shared__ __align__(16) float Bs[8][132];
  int tid = threadIdx.x;
  int o0 = blockIdx.x * 128;
  int j0 = blockIdx.y * 128;
  int b = j0 >> 11, n0 = j0 & (N_ - 1);
  int ty = tid >> 4, tx = tid & 15;
  float acc[8][8] = {};
  int aO = tid & 127, aKb = tid >> 7;        // A: o = aO, kk = aKb + 2q
  int bK = tid >> 5, bj4 = (tid & 31) << 2;  // B: kk = bK, j = bj4..+3
#pragma unroll 1
  for (int k0 = 0; k0 < K; k0 += 8) {
    __syncthreads();
#pragma unroll
    for (int q = 0; q < 4; ++q) {
      int kk = aKb + (q << 1);
      As[kk][aO] = Wm[(long)(o0 + aO) * K + k0 + kk];
    }
    {
      int c = k0 + bK;
      const float* src = (c < Dx) ? xin + (long)b * bstr + (long)c * N_
                                  : agg + (long)b * aggbstr + (long)(c - Dx) * N_;
      *(float4*)&Bs[bK][bj4] = *(const float4*)(src + n0 + bj4);
    }
    __syncthreads();
#pragma unroll
    for (int kk = 0; kk < 8; ++kk) {
      float4 alo = *(const float4*)&As[kk][ty << 2];
      float4 ahi = *(const float4*)&As[kk][64 + (ty << 2)];
      float4 blo = *(const float4*)&Bs[kk][tx << 2];
      float4 bhi = *(const float4*)&Bs[kk][64 + (tx << 2)];
      float av[8] = {alo.x, alo.y, alo.z, alo.w, ahi.x, ahi.y, ahi.z, ahi.w};
      float bv[8] = {blo.x, blo.y, blo.z, blo.w, bhi.x, bhi.y, bhi.z, bhi.w};
#pragma unroll
      for (int r = 0; r < 8; ++r)
#pragma unroll
        for (int c = 0; c < 8; ++c) acc[r][c] = fmaf(av[r], bv[c], acc[r][c]);
    }
  }
#pragma unroll
  for (int r = 0; r < 8; ++r) {
    int o = o0 + ((r < 4) ? (ty << 2) + r : 64 + (ty << 2) + (r - 4));
    float4 vlo, vhi;
    vlo.x = acc[r][0]; vlo.y = acc[r][1]; vlo.z = acc[r][2]; vlo.w = acc[r][3];
    vhi.x = acc[r][4]; vhi.y = acc[r][5]; vhi.z = acc[r][6]; vhi.w = acc[r][7];
    float* yrow = y + ((long)b * O + o) * N_ + n0;
    *(float4*)(yrow + (tx << 2)) = vlo;
    *(float4*)(yrow + 64 + (tx << 2)) = vhi;
    float s1 = vlo.x + vlo.y + vlo.z + vlo.w + vhi.x + vhi.y + vhi.z + vhi.w;
    float s2 = vlo.x * vlo.x + vlo.y * vlo.y + vlo.z * vlo.z + vlo.w * vlo.w +
               vhi.x * vhi.x + vhi.y * vhi.y + vhi.z * vhi.z + vhi.w * vhi.w;
#pragma unroll
    for (int off = 1; off < 16; off <<= 1) { s1 += __shfl_xor(s1, off); s2 += __shfl_xor(s2, off); }
    if (tx == 0) { atomicAdd(&stats[o], s1); atomicAdd(&stats[O + o], s2); }
  }
}

// ============================================================ fold BN stats into scale/shift
__global__ __launch_bounds__(256) void bn_finalize_kernel(float* __restrict__ stats,
                                                          const float* __restrict__ g,
                                                          const float* __restrict__ be, int O) {
  int o = blockIdx.x * 256 + threadIdx.x;
  if (o >= O) return;
  const float inv_cnt = 1.f / (B_ * (float)N_);
  float mean = stats[o] * inv_cnt;
  float var = stats[O + o] * inv_cnt - mean * mean;
  float a = g[o] * rsqrtf(var + BN_EPS);
  float bb = be[o] - mean * a;
  stats[o] = a;
  stats[O + o] = bb;
}

// ============================================================ y -> lrelu(a*y+b) -> dst (+dst2)
__global__ __launch_bounds__(256) void bn_apply_kernel(const float* __restrict__ y,
                                                       const float* __restrict__ stats, int O,
                                                       float* __restrict__ dst, int c0, int dstStride,
                                                       float* __restrict__ dst2) {
  long i4 = (long)blockIdx.x * 256 + threadIdx.x;
  long total4 = (long)B_ * O * N_ / 4;
  if (i4 >= total4) return;
  long i = i4 << 2;
  int ob = __ffs(O) - 1;
  int o = (int)((i >> 11) & (O - 1));
  int b = (int)(i >> (11 + ob));
  int n = (int)(i & (N_ - 1));
  float a = stats[o], bb = stats[O + o];
  float4 v = *(const float4*)(y + i);
  v.x = fmaf(a, v.x, bb); v.x = v.x >= 0.f ? v.x : SLOPE * v.x;
  v.y = fmaf(a, v.y, bb); v.y = v.y >= 0.f ? v.y : SLOPE * v.y;
  v.z = fmaf(a, v.z, bb); v.z = v.z >= 0.f ? v.z : SLOPE * v.z;
  v.w = fmaf(a, v.w, bb); v.w = v.w >= 0.f ? v.w : SLOPE * v.w;
  *(float4*)(dst + ((long)b * dstStride + c0 + o) * N_ + n) = v;
  if (dst2) *(float4*)(dst2 + i) = v;
}

// ============================================================ launcher
extern "C" void kernel_launch(void* const* d_in, const int* in_sizes, int n_in,
                              void* d_out, int out_size, void* d_ws, size_t ws_size,
                              hipStream_t stream) {
  const float* x = (const float*)d_in[0];
  const float* W[5];
  const float* gm[5];
  const float* bt[5];
  for (int i = 0; i < 5; ++i) W[i] = (const float*)d_in[1 + i];
  for (int i = 0; i < 5; ++i) { gm[i] = (const float*)d_in[6 + 2 * i]; bt[i] = (const float*)d_in[7 + 2 * i]; }

  const long XBS = 512L * N_;                     // xall per-batch stride (floats)
  float* xall = (float*)d_ws;                     // (B, 512, N): x1@ch0, x2@ch64, x3@ch128, x4@ch256
  float* xxb = xall + (long)B_ * XBS;             // (B, N)
  float* stats = xxb + (long)B_ * N_;             // 5 * 1024
  float* xTb = xall + 256L * N_;                  // per-batch (N, D) in xall ch256..383 (spare until L4 apply)
  float* aggb = xall + 384L * N_;                 // per-batch (D, N) in xall ch384..511
  float* yb = (float*)d_out;                      // (B, O, N), max = x5 slot exactly
  float* outB = (float*)d_out + (long)B_ * XBS;   // x3 output slot

  hipMemsetAsync(stats, 0, 5 * 1024 * sizeof(float), stream);

  struct LayerCfg { const float* xin; long bstr; int D; int O; int c0; };
  LayerCfg L[4] = {
      {x, 3L * N_, 3, 64, 0},
      {xall, XBS, 64, 64, 64},
      {xall + 64L * N_, XBS, 64, 128, 128},
      {xall + 128L * N_, XBS, 128, 256, 256},
  };

  for (int li = 0; li < 4; ++li) {
    const LayerCfg c = L[li];
    float* st = stats + li * 1024;
    xx_kernel<<<B_ * N_ / 256, 256, 0, stream>>>(c.xin, c.bstr, c.D, xxb);
    transpose_kernel<<<dim3(N_ / 64, B_), 256, 0, stream>>>(c.xin, c.bstr, xTb, XBS, c.D);
    if (c.D == 3)
      gsa_blk_kernel<3><<<B_ * N_ / 16, 256, 0, stream>>>(c.xin, c.bstr, xTb, XBS, xxb, aggb, XBS);
    else if (c.D == 64)
      gsa_blk_kernel<64><<<B_ * N_ / 16, 256, 0, stream>>>(c.xin, c.bstr, xTb, XBS, xxb, aggb, XBS);
    else
      gsa_blk_kernel<128><<<B_ * N_ / 16, 256, 0, stream>>>(c.xin, c.bstr, xTb, XBS, xxb, aggb, XBS);
    int K = 2 * c.D;
    if (c.O >= 128 && (K % 8) == 0)
      gemm_bn128_kernel<<<dim3(c.O / 128, B_ * N_ / 128), 256, 0, stream>>>(
          W[li], c.O, K, c.xin, c.bstr, c.D, aggb, XBS, yb, st);
    else
      gemm_bn_kernel<<<dim3(c.O / 64, B_ * N_ / 64), 256, 0, stream>>>(
          W[li], c.O, K, c.xin, c.bstr, c.D, aggb, XBS, yb, st);
    bn_finalize_kernel<<<(c.O + 255) / 256, 256, 0, stream>>>(st, gm[li], bt[li], c.O);
    long t4 = (long)B_ * c.O * N_ / 4;
    bn_apply_kernel<<<(int)((t4 + 255) / 256), 256, 0, stream>>>(
        yb, st, c.O, xall, c.c0, 512, (li == 2) ? outB : nullptr);
  }
  // layer 5: plain conv on the concat (xall ch0..511), no gsa
  {
    float* st = stats + 4 * 1024;
    gemm_bn128_kernel<<<dim3(512 / 128, B_ * N_ / 128), 256, 0, stream>>>(
        W[4], 512, 512, xall, XBS, 512, nullptr, XBS, yb, st);
    bn_finalize_kernel<<<2, 256, 0, stream>>>(st, gm[4], bt[4], 512);
    long t4 = (long)B_ * 512 * N_ / 4;
    bn_apply_kernel<<<(int)((t4 + 255) / 256), 256, 0, stream>>>(yb, st, 512, yb, 0, 512, nullptr);
  }
}

// Round 5
// 2285.176 us; speedup vs baseline: 1.8859x; 1.8859x over previous
//
#include <hip/hip_runtime.h>
#include <math.h>

#define B_ 16
#define N_ 2048
#define KNN 20
#define BN_EPS 1e-5f
#define SLOPE 0.01f

// ============================================================ xx = sum_d x^2
__global__ __launch_bounds__(256) void xx_kernel(const float* __restrict__ xin, long bstr, int D,
                                                 float* __restrict__ xx) {
  int i = blockIdx.x * 256 + threadIdx.x;
  if (i >= B_ * N_) return;
  int b = i >> 11, n = i & (N_ - 1);
  const float* p = xin + (long)b * bstr + n;
  float s = 0.f;
#pragma unroll 1
  for (int d = 0; d < D; ++d) { float v = p[(long)d * N_]; s = fmaf(v, v, s); }
  xx[i] = s;
}

// ============================================================ (B,D,N) -> per-batch (N,D)
__global__ __launch_bounds__(256) void transpose_kernel(const float* __restrict__ xin, long bstr,
                                                        float* __restrict__ xT, long xTbstr, int D) {
  __shared__ float s[32][65];
  int b = blockIdx.y;
  int n0 = blockIdx.x * 64;
  int tid = threadIdx.x;
  const float* xb = xin + (long)b * bstr;
  float* tb = xT + (long)b * xTbstr;
  for (int dc = 0; dc < D; dc += 32) {
    for (int i = tid; i < 32 * 64; i += 256) {
      int d = i >> 6, n = i & 63;
      s[d][n] = (dc + d < D) ? xb[(long)(dc + d) * N_ + n0 + n] : 0.f;
    }
    __syncthreads();
    for (int i = tid; i < 64 * 32; i += 256) {
      int n = i >> 5, d = i & 31;
      if (dc + d < D) tb[(long)(n0 + n) * D + dc + d] = s[d][n];
    }
    __syncthreads();
  }
}

// ============================================================ streaming gsa:
//  4 waves/block, 4 rows/wave in registers (acc[4][8] float4). x streamed from L2
//  with double-buffered row prefetch; NO LDS staging, NO per-chunk barriers.
//  top-20: chunk-max scan + 6-step butterfly, 4 rows interleaved per iteration.
template <int D>
__global__ __launch_bounds__(256, 2) void gsa_stream_kernel(const float* __restrict__ xin, long bstr,
                                                            const float* __restrict__ xT, long xTbstr,
                                                            const float* __restrict__ xx,
                                                            float* __restrict__ agg, long aggbstr) {
  constexpr int NV = (D + 63) / 64;
  __shared__ float xn_s[16][((D + 3) & ~3)];
  int tid = threadIdx.x, w = tid >> 6, lane = tid & 63;
  int r0 = blockIdx.x * 16;
  int b = r0 >> 11, n0 = r0 & (N_ - 1);
  const float* xb = xin + (long)b * bstr;
  const float* tb = xT + (long)b * xTbstr;
  for (int i = tid; i < 16 * D; i += 256) {
    int rr = i / D, d = i - rr * D;
    xn_s[rr][d] = tb[(long)(n0 + rr) * D + d];
  }
  __syncthreads();

  float4 acc[4][8];  // [row][chunk]; col = 256*c + 4*lane + j
#pragma unroll
  for (int r = 0; r < 4; ++r)
#pragma unroll
    for (int c = 0; c < 8; ++c) acc[r][c] = make_float4(0.f, 0.f, 0.f, 0.f);

  float4 bufA[8], bufB[8];
  {
    const float4* xrow = (const float4*)xb;
#pragma unroll
    for (int c = 0; c < 8; ++c) bufA[c] = xrow[c * 64 + lane];
  }

#define FMA_STEP(BUF, dd)                                              \
  {                                                                    \
    _Pragma("unroll") for (int r = 0; r < 4; ++r) {                    \
      float xnd = xn_s[(w << 2) + r][dd];                              \
      _Pragma("unroll") for (int c = 0; c < 8; ++c) {                  \
        acc[r][c].x = fmaf(xnd, BUF[c].x, acc[r][c].x);                \
        acc[r][c].y = fmaf(xnd, BUF[c].y, acc[r][c].y);                \
        acc[r][c].z = fmaf(xnd, BUF[c].z, acc[r][c].z);                \
        acc[r][c].w = fmaf(xnd, BUF[c].w, acc[r][c].w);                \
      }                                                                \
    }                                                                  \
  }

#pragma unroll 1
  for (int d = 0; d < D; d += 2) {
    if (d + 1 < D) {
      const float4* xrow = (const float4*)(xb + (long)(d + 1) * N_);
#pragma unroll
      for (int c = 0; c < 8; ++c) bufB[c] = xrow[c * 64 + lane];
    }
    FMA_STEP(bufA, d);
    if (d + 2 < D) {
      const float4* xrow = (const float4*)(xb + (long)(d + 2) * N_);
#pragma unroll
      for (int c = 0; c < 8; ++c) bufA[c] = xrow[c * 64 + lane];
    }
    if (d + 1 < D) FMA_STEP(bufB, d + 1);
  }
#undef FMA_STEP

  // acc -> dist in place: dv = 2*acc - xx[n] - xx[m]
  {
    const float4* xx4 = (const float4*)(xx + (long)b * N_);
    float4 xm[8];
#pragma unroll
    for (int c = 0; c < 8; ++c) xm[c] = xx4[c * 64 + lane];
#pragma unroll
    for (int r = 0; r < 4; ++r) {
      float xxn = xx[(long)b * N_ + n0 + (w << 2) + r];
#pragma unroll
      for (int c = 0; c < 8; ++c) {
        acc[r][c].x = 2.f * acc[r][c].x - xxn - xm[c].x;
        acc[r][c].y = 2.f * acc[r][c].y - xxn - xm[c].y;
        acc[r][c].z = 2.f * acc[r][c].z - xxn - xm[c].z;
        acc[r][c].w = 2.f * acc[r][c].w - xxn - xm[c].w;
      }
    }
  }

  // chunk maxes: m8[r][c] value, sspack[r] holds 2-bit argmax-j per chunk
  float m8[4][8];
  int sspack[4];
#pragma unroll
  for (int r = 0; r < 4; ++r) {
    int sp = 0;
#pragma unroll
    for (int c = 0; c < 8; ++c) {
      const float* av = (const float*)&acc[r][c];
      float mm = av[0]; int ss = 0;
      if (av[1] > mm) { mm = av[1]; ss = 1; }
      if (av[2] > mm) { mm = av[2]; ss = 2; }
      if (av[3] > mm) { mm = av[3]; ss = 3; }
      m8[r][c] = mm; sp |= ss << (2 * c);
    }
    sspack[r] = sp;
  }

  float Z[4] = {0.f, 0.f, 0.f, 0.f};
  float m0[4];
  float ve[4][NV];
#pragma unroll
  for (int r = 0; r < 4; ++r)
#pragma unroll
    for (int vi = 0; vi < NV; ++vi) ve[r][vi] = 0.f;

#pragma unroll 1
  for (int it = 0; it < KNN; ++it) {
    float best[4]; int bidx[4];
#pragma unroll
    for (int r = 0; r < 4; ++r) {
      int sp = sspack[r];
      float bv = m8[r][0]; int bi = (lane << 2) + (sp & 3);
#pragma unroll
      for (int c = 1; c < 8; ++c) {
        float v = m8[r][c];
        int cand = (c << 8) + (lane << 2) + ((sp >> (2 * c)) & 3);
        if (v > bv) { bv = v; bi = cand; }
      }
      best[r] = bv; bidx[r] = bi;
    }
    // 4 rows' butterflies interleaved -> 4-deep ILP on the shfl chains
#pragma unroll
    for (int off = 1; off < 64; off <<= 1) {
#pragma unroll
      for (int r = 0; r < 4; ++r) {
        float ov = __shfl_xor(best[r], off);
        int oi = __shfl_xor(bidx[r], off);
        if (ov > best[r] || (ov == best[r] && oi < bidx[r])) { best[r] = ov; bidx[r] = oi; }
      }
    }
#pragma unroll
    for (int r = 0; r < 4; ++r) {
      int ub = __builtin_amdgcn_readfirstlane(bidx[r]);   // ub == winning column
      if (it == 0) m0[r] = best[r];
      float e = __expf(best[r] - m0[r]);
      Z[r] += e;
#pragma unroll
      for (int vi = 0; vi < NV; ++vi) {
        int dd = lane + (vi << 6);
        if (D >= 64 || dd < D) ve[r][vi] = fmaf(e, tb[(long)ub * D + dd], ve[r][vi]);
      }
      // remove winner + rescan its chunk (uniform chunk branch, static indexing)
      int cw = ub >> 8, jw = ub & 3;
      bool isw = (lane == ((ub >> 2) & 63));
#pragma unroll
      for (int c = 0; c < 8; ++c)
        if (c == cw) {
          float* av = (float*)&acc[r][c];
#pragma unroll
          for (int j = 0; j < 4; ++j)
            if (j == jw && isw) av[j] = -3.4e38f;
          float mm = av[0]; int ss = 0;
          if (av[1] > mm) { mm = av[1]; ss = 1; }
          if (av[2] > mm) { mm = av[2]; ss = 2; }
          if (av[3] > mm) { mm = av[3]; ss = 3; }
          m8[r][c] = mm;
          sspack[r] = (sspack[r] & ~(3 << (2 * c))) | (ss << (2 * c));
        }
    }
  }

#pragma unroll
  for (int r = 0; r < 4; ++r) {
    float rZ = 1.f / Z[r];
    int n = n0 + (w << 2) + r;
#pragma unroll
    for (int vi = 0; vi < NV; ++vi) {
      int dd = lane + (vi << 6);
      if (D >= 64 || dd < D)
        agg[(long)b * aggbstr + (long)dd * N_ + n] = ve[r][vi] * rZ - xn_s[(w << 2) + r][dd];
    }
  }
}

// ============================================================ small GEMM (64x64 tile) + BN stats
__global__ __launch_bounds__(256) void gemm_bn_kernel(const float* __restrict__ Wm, int O, int K,
                                                      const float* __restrict__ xin, long bstr, int Dx,
                                                      const float* __restrict__ agg, long aggbstr,
                                                      float* __restrict__ y, float* __restrict__ stats) {
  __shared__ __align__(16) float As[16][68];
  __shared__ __align__(16) float Bs[16][68];
  int tid = threadIdx.x;
  int o0 = blockIdx.x * 64;
  int j0 = blockIdx.y * 64;
  int b = j0 >> 11, n0 = j0 & (N_ - 1);
  int ty = tid >> 4, tx = tid & 15;
  float accr[4][4] = {};
  int aK = tid & 15, aO = tid >> 4;
  int bK = tid >> 4, bn4 = (tid & 15) << 2;
  for (int k0 = 0; k0 < K; k0 += 16) {
#pragma unroll
    for (int q = 0; q < 4; ++q) {
      int o = aO + (q << 4);
      As[aK][o] = (k0 + aK < K) ? Wm[(long)(o0 + o) * K + k0 + aK] : 0.f;
    }
    {
      int c = k0 + bK;
      float4 v = {0.f, 0.f, 0.f, 0.f};
      if (c < K) {
        const float* src = (c < Dx) ? xin + (long)b * bstr + (long)c * N_
                                    : agg + (long)b * aggbstr + (long)(c - Dx) * N_;
        v = *(const float4*)(src + n0 + bn4);
      }
      *(float4*)&Bs[bK][bn4] = v;
    }
    __syncthreads();
#pragma unroll
    for (int kk = 0; kk < 16; ++kk) {
      float4 a4 = *(const float4*)&As[kk][ty << 2];
      float4 b4 = *(const float4*)&Bs[kk][tx << 2];
      accr[0][0] = fmaf(a4.x, b4.x, accr[0][0]);
      accr[0][1] = fmaf(a4.x, b4.y, accr[0][1]);
      accr[0][2] = fmaf(a4.x, b4.z, accr[0][2]);
      accr[0][3] = fmaf(a4.x, b4.w, accr[0][3]);
      accr[1][0] = fmaf(a4.y, b4.x, accr[1][0]);
      accr[1][1] = fmaf(a4.y, b4.y, accr[1][1]);
      accr[1][2] = fmaf(a4.y, b4.z, accr[1][2]);
      accr[1][3] = fmaf(a4.y, b4.w, accr[1][3]);
      accr[2][0] = fmaf(a4.z, b4.x, accr[2][0]);
      accr[2][1] = fmaf(a4.z, b4.y, accr[2][1]);
      accr[2][2] = fmaf(a4.z, b4.z, accr[2][2]);
      accr[2][3] = fmaf(a4.z, b4.w, accr[2][3]);
      accr[3][0] = fmaf(a4.w, b4.x, accr[3][0]);
      accr[3][1] = fmaf(a4.w, b4.y, accr[3][1]);
      accr[3][2] = fmaf(a4.w, b4.z, accr[3][2]);
      accr[3][3] = fmaf(a4.w, b4.w, accr[3][3]);
    }
    __syncthreads();
  }
#pragma unroll
  for (int r = 0; r < 4; ++r) {
    int o = o0 + (ty << 2) + r;
    float4 v;
    v.x = accr[r][0]; v.y = accr[r][1]; v.z = accr[r][2]; v.w = accr[r][3];
    *(float4*)(y + ((long)b * O + o) * N_ + n0 + bn4) = v;
    float s1 = v.x + v.y + v.z + v.w;
    float s2 = v.x * v.x + v.y * v.y + v.z * v.z + v.w * v.w;
#pragma unroll
    for (int off = 1; off < 16; off <<= 1) { s1 += __shfl_xor(s1, off); s2 += __shfl_xor(s2, off); }
    if (tx == 0) { atomicAdd(&stats[o], s1); atomicAdd(&stats[O + o], s2); }
  }
}

// ============================================================ big GEMM (128x128x8 tile) + BN stats
__global__ __launch_bounds__(256) void gemm_bn128_kernel(const float* __restrict__ Wm, int O, int K,
                                                         const float* __restrict__ xin, long bstr, int Dx,
                                                         const float* __restrict__ agg, long aggbstr,
                                                         float* __restrict__ y, float* __restrict__ stats) {
  __shared__ __align__(16) float As[8][132];
  __shared__ __align__(16) float Bs[8][132];
  int tid = threadIdx.x;
  int o0 = blockIdx.x * 128;
  int j0 = blockIdx.y * 128;
  int b = j0 >> 11, n0 = j0 & (N_ - 1);
  int ty = tid >> 4, tx = tid & 15;
  float acc[8][8] = {};
  int aO = tid & 127, aKb = tid >> 7;
  int bK = tid >> 5, bj4 = (tid & 31) << 2;
#pragma unroll 1
  for (int k0 = 0; k0 < K; k0 += 8) {
    __syncthreads();
#pragma unroll
    for (int q = 0; q < 4; ++q) {
      int kk = aKb + (q << 1);
      As[kk][aO] = Wm[(long)(o0 + aO) * K + k0 + kk];
    }
    {
      int c = k0 + bK;
      const float* src = (c < Dx) ? xin + (long)b * bstr + (long)c * N_
                                  : agg + (long)b * aggbstr + (long)(c - Dx) * N_;
      *(float4*)&Bs[bK][bj4] = *(const float4*)(src + n0 + bj4);
    }
    __syncthreads();
#pragma unroll
    for (int kk = 0; kk < 8; ++kk) {
      float4 alo = *(const float4*)&As[kk][ty << 2];
      float4 ahi = *(const float4*)&As[kk][64 + (ty << 2)];
      float4 blo = *(const float4*)&Bs[kk][tx << 2];
      float4 bhi = *(const float4*)&Bs[kk][64 + (tx << 2)];
      float av[8] = {alo.x, alo.y, alo.z, alo.w, ahi.x, ahi.y, ahi.z, ahi.w};
      float bv[8] = {blo.x, blo.y, blo.z, blo.w, bhi.x, bhi.y, bhi.z, bhi.w};
#pragma unroll
      for (int r = 0; r < 8; ++r)
#pragma unroll
        for (int c = 0; c < 8; ++c) acc[r][c] = fmaf(av[r], bv[c], acc[r][c]);
    }
  }
#pragma unroll
  for (int r = 0; r < 8; ++r) {
    int o = o0 + ((r < 4) ? (ty << 2) + r : 64 + (ty << 2) + (r - 4));
    float4 vlo, vhi;
    vlo.x = acc[r][0]; vlo.y = acc[r][1]; vlo.z = acc[r][2]; vlo.w = acc[r][3];
    vhi.x = acc[r][4]; vhi.y = acc[r][5]; vhi.z = acc[r][6]; vhi.w = acc[r][7];
    float* yrow = y + ((long)b * O + o) * N_ + n0;
    *(float4*)(yrow + (tx << 2)) = vlo;
    *(float4*)(yrow + 64 + (tx << 2)) = vhi;
    float s1 = vlo.x + vlo.y + vlo.z + vlo.w + vhi.x + vhi.y + vhi.z + vhi.w;
    float s2 = vlo.x * vlo.x + vlo.y * vlo.y + vlo.z * vlo.z + vlo.w * vlo.w +
               vhi.x * vhi.x + vhi.y * vhi.y + vhi.z * vhi.z + vhi.w * vhi.w;
#pragma unroll
    for (int off = 1; off < 16; off <<= 1) { s1 += __shfl_xor(s1, off); s2 += __shfl_xor(s2, off); }
    if (tx == 0) { atomicAdd(&stats[o], s1); atomicAdd(&stats[O + o], s2); }
  }
}

// ============================================================ fold BN stats into scale/shift
__global__ __launch_bounds__(256) void bn_finalize_kernel(float* __restrict__ stats,
                                                          const float* __restrict__ g,
                                                          const float* __restrict__ be, int O) {
  int o = blockIdx.x * 256 + threadIdx.x;
  if (o >= O) return;
  const float inv_cnt = 1.f / (B_ * (float)N_);
  float mean = stats[o] * inv_cnt;
  float var = stats[O + o] * inv_cnt - mean * mean;
  float a = g[o] * rsqrtf(var + BN_EPS);
  float bb = be[o] - mean * a;
  stats[o] = a;
  stats[O + o] = bb;
}

// ============================================================ y -> lrelu(a*y+b) -> dst (+dst2)
__global__ __launch_bounds__(256) void bn_apply_kernel(const float* __restrict__ y,
                                                       const float* __restrict__ stats, int O,
                                                       float* __restrict__ dst, int c0, int dstStride,
                                                       float* __restrict__ dst2) {
  long i4 = (long)blockIdx.x * 256 + threadIdx.x;
  long total4 = (long)B_ * O * N_ / 4;
  if (i4 >= total4) return;
  long i = i4 << 2;
  int ob = __ffs(O) - 1;
  int o = (int)((i >> 11) & (O - 1));
  int b = (int)(i >> (11 + ob));
  int n = (int)(i & (N_ - 1));
  float a = stats[o], bb = stats[O + o];
  float4 v = *(const float4*)(y + i);
  v.x = fmaf(a, v.x, bb); v.x = v.x >= 0.f ? v.x : SLOPE * v.x;
  v.y = fmaf(a, v.y, bb); v.y = v.y >= 0.f ? v.y : SLOPE * v.y;
  v.z = fmaf(a, v.z, bb); v.z = v.z >= 0.f ? v.z : SLOPE * v.z;
  v.w = fmaf(a, v.w, bb); v.w = v.w >= 0.f ? v.w : SLOPE * v.w;
  *(float4*)(dst + ((long)b * dstStride + c0 + o) * N_ + n) = v;
  if (dst2) *(float4*)(dst2 + i) = v;
}

// ============================================================ launcher
extern "C" void kernel_launch(void* const* d_in, const int* in_sizes, int n_in,
                              void* d_out, int out_size, void* d_ws, size_t ws_size,
                              hipStream_t stream) {
  const float* x = (const float*)d_in[0];
  const float* W[5];
  const float* gm[5];
  const float* bt[5];
  for (int i = 0; i < 5; ++i) W[i] = (const float*)d_in[1 + i];
  for (int i = 0; i < 5; ++i) { gm[i] = (const float*)d_in[6 + 2 * i]; bt[i] = (const float*)d_in[7 + 2 * i]; }

  const long XBS = 512L * N_;                     // xall per-batch stride (floats)
  float* xall = (float*)d_ws;                     // (B, 512, N): x1@ch0, x2@ch64, x3@ch128, x4@ch256
  float* xxb = xall + (long)B_ * XBS;             // (B, N)
  float* stats = xxb + (long)B_ * N_;             // 5 * 1024
  float* xTb = xall + 256L * N_;                  // per-batch (N, D) in xall ch256..383 (spare until L4 apply)
  float* aggb = xall + 384L * N_;                 // per-batch (D, N) in xall ch384..511
  float* yb = (float*)d_out;                      // (B, O, N), max = x5 slot exactly
  float* outB = (float*)d_out + (long)B_ * XBS;   // x3 output slot

  hipMemsetAsync(stats, 0, 5 * 1024 * sizeof(float), stream);

  struct LayerCfg { const float* xin; long bstr; int D; int O; int c0; };
  LayerCfg L[4] = {
      {x, 3L * N_, 3, 64, 0},
      {xall, XBS, 64, 64, 64},
      {xall + 64L * N_, XBS, 64, 128, 128},
      {xall + 128L * N_, XBS, 128, 256, 256},
  };

  for (int li = 0; li < 4; ++li) {
    const LayerCfg c = L[li];
    float* st = stats + li * 1024;
    xx_kernel<<<B_ * N_ / 256, 256, 0, stream>>>(c.xin, c.bstr, c.D, xxb);
    transpose_kernel<<<dim3(N_ / 64, B_), 256, 0, stream>>>(c.xin, c.bstr, xTb, XBS, c.D);
    if (c.D == 3)
      gsa_stream_kernel<3><<<B_ * N_ / 16, 256, 0, stream>>>(c.xin, c.bstr, xTb, XBS, xxb, aggb, XBS);
    else if (c.D == 64)
      gsa_stream_kernel<64><<<B_ * N_ / 16, 256, 0, stream>>>(c.xin, c.bstr, xTb, XBS, xxb, aggb, XBS);
    else
      gsa_stream_kernel<128><<<B_ * N_ / 16, 256, 0, stream>>>(c.xin, c.bstr, xTb, XBS, xxb, aggb, XBS);
    int K = 2 * c.D;
    if (c.O >= 128 && (K % 8) == 0)
      gemm_bn128_kernel<<<dim3(c.O / 128, B_ * N_ / 128), 256, 0, stream>>>(
          W[li], c.O, K, c.xin, c.bstr, c.D, aggb, XBS, yb, st);
    else
      gemm_bn_kernel<<<dim3(c.O / 64, B_ * N_ / 64), 256, 0, stream>>>(
          W[li], c.O, K, c.xin, c.bstr, c.D, aggb, XBS, yb, st);
    bn_finalize_kernel<<<(c.O + 255) / 256, 256, 0, stream>>>(st, gm[li], bt[li], c.O);
    long t4 = (long)B_ * c.O * N_ / 4;
    bn_apply_kernel<<<(int)((t4 + 255) / 256), 256, 0, stream>>>(
        yb, st, c.O, xall, c.c0, 512, (li == 2) ? outB : nullptr);
  }
  // layer 5: plain conv on the concat (xall ch0..511), no gsa
  {
    float* st = stats + 4 * 1024;
    gemm_bn128_kernel<<<dim3(512 / 128, B_ * N_ / 128), 256, 0, stream>>>(
        W[4], 512, 512, xall, XBS, 512, nullptr, XBS, yb, st);
    bn_finalize_kernel<<<2, 256, 0, stream>>>(st, gm[4], bt[4], 512);
    long t4 = (long)B_ * 512 * N_ / 4;
    bn_apply_kernel<<<(int)((t4 + 255) / 256), 256, 0, stream>>>(yb, st, 512, yb, 0, 512, nullptr);
  }
}